// Round 11
// baseline (1160.345 us; speedup 1.0000x reference)
//
#include <hip/hip_runtime.h>
#include <hip/hip_bf16.h>

// R11: wave-autonomous, zero-barrier kernels with coalesced loads + wave-private
// LDS transpose (fixes R7/R10's lane-major loads and R10's register spill).
// kA: scores over 25600 16-row tiles, grid-stride per wave.
// kB: wave-owns-m: softmax + v-GEMM(K=256, 7 tiles) + pooling + lout.

#define M_ 4096
#define N_ 100
#define E_ 128
#define R_ (M_ * N_)          // 409600 rows; 25600 16-row tiles exactly

typedef __bf16 bf16x8 __attribute__((ext_vector_type(8)));
typedef float  f32x4  __attribute__((ext_vector_type(4)));

// W1p[ck][n][j] = bf16(W1[ck*8+j][n]), ck<48 ; WRp same for WR, ck<32 ;
// Wot[e][k] = Wo[k][e]
__global__ void prep_weights(const float* __restrict__ W1, const float* __restrict__ WR,
                             const float* __restrict__ Wo,
                             __bf16* __restrict__ W1p, __bf16* __restrict__ WRp,
                             float* __restrict__ Wot) {
    int i = blockIdx.x * 256 + threadIdx.x;   // 384*256 = 49152+32768+16384
    if (i < 48 * 128 * 8) {
        int ck = i >> 10, n = (i >> 3) & 127, j = i & 7;
        W1p[i] = (__bf16)W1[(ck * 8 + j) * 128 + n];
    } else if (i < 48 * 128 * 8 + 32 * 128 * 8) {
        int t = i - 48 * 128 * 8;
        int ck = t >> 10, n = (t >> 3) & 127, j = t & 7;
        WRp[t] = (__bf16)WR[(ck * 8 + j) * 128 + n];
    } else {
        int t = i - (48 * 128 * 8 + 32 * 128 * 8);
        int e = t >> 7, k = t & 127;
        Wot[t] = Wo[k * 128 + e];
    }
}

// coalesced chunk load: 16 rows x 64 k f32; lane -> row g+4j, cols l15*4..+4
__device__ __forceinline__ void loadCh(float4 (&xv)[4], const float* __restrict__ src,
                                       int co, int l15, int g) {
    #pragma unroll
    for (int j = 0; j < 4; ++j)
        xv[j] = *reinterpret_cast<const float4*>(src + (long)(g + 4 * j) * E_ + co + l15 * 4);
}
// clamped variant (kB pad rows -> row 99, masked later by weight=0)
__device__ __forceinline__ void loadChB(float4 (&xv)[4], const float* __restrict__ src,
                                        int r0, int co, int l15, int g) {
    #pragma unroll
    for (int j = 0; j < 4; ++j) {
        int r = r0 + g + 4 * j; if (r > N_ - 1) r = N_ - 1;
        xv[j] = *reinterpret_cast<const float4*>(src + (long)r * E_ + co + l15 * 4);
    }
}
// cvt + swizzled wave-private LDS write: elem (row, k l15*4..+4)
__device__ __forceinline__ void writeCh(float4 (&xv)[4], __bf16* xb, int l15, int g) {
    #pragma unroll
    for (int j = 0; j < 4; ++j) {
        const int row = g + 4 * j;
        const int blk = (l15 >> 1) ^ (row & 7);
        union { __bf16 h[4]; uint2 u; } w;
        w.h[0] = (__bf16)xv[j].x; w.h[1] = (__bf16)xv[j].y;
        w.h[2] = (__bf16)xv[j].z; w.h[3] = (__bf16)xv[j].w;
        *reinterpret_cast<uint2*>(xb + row * 64 + blk * 8 + (l15 & 1) * 4) = w.u;
    }
}
// one K=64 chunk of MFMA: A from wave LDS (swizzled), B from chunked weights
__device__ __forceinline__ void computeCh(const __bf16* xb, const __bf16* __restrict__ Wp,
                                          int k32, f32x4 (&acc)[8], int l15, int g) {
    #pragma unroll
    for (int ks = 0; ks < 2; ++ks) {
        bf16x8 af = *reinterpret_cast<const bf16x8*>(
            xb + l15 * 64 + ((((ks << 2) + g)) ^ (l15 & 7)) * 8);
        const __bf16* wp = Wp + ((long)((k32 + ks) * 4 + g) << 10) + l15 * 8;
        #pragma unroll
        for (int cf = 0; cf < 8; ++cf) {
            bf16x8 bf = *reinterpret_cast<const bf16x8*>(wp + (cf << 7));
            acc[cf] = __builtin_amdgcn_mfma_f32_16x16x32_bf16(af, bf, acc[cf], 0, 0, 0);
        }
    }
}

// ---------------- kernel A ----------------
__global__ __launch_bounds__(256, 3) void kA(
    const float* __restrict__ pus, const float* __restrict__ pis,
    const float* __restrict__ pss,
    const __bf16* __restrict__ W1p, const float* __restrict__ b1,
    const float* __restrict__ W2, const float* __restrict__ b2,
    float* __restrict__ scores)
{
    __shared__ __align__(16) __bf16 Xw[4][2][1024];

    const int tid = threadIdx.x;
    const int lane = tid & 63;
    const int wid  = tid >> 6;
    const int g    = lane >> 4;
    const int l15  = lane & 15;
    const int gw = blockIdx.x * 4 + wid;
    const int NW = gridDim.x * 4;

    float w2v[8], b1v[8];
    #pragma unroll
    for (int cf = 0; cf < 8; ++cf) {
        w2v[cf] = W2[cf * 16 + l15];
        b1v[cf] = b1[cf * 16 + l15];
    }
    const float b2v = b2[0];

    __bf16* xb0 = &Xw[wid][0][0];
    __bf16* xb1 = &Xw[wid][1][0];

    for (int t = gw; t < R_ / 16; t += NW) {
        const float* __restrict__ pu = pus + (long)t * 16 * E_;
        const float* __restrict__ pi = pis + (long)t * 16 * E_;
        const float* __restrict__ ps = pss + (long)t * 16 * E_;

        float4 xvE[4], xvO[4];
        loadCh(xvE, pu, 0, l15, g);
        loadCh(xvO, pu, 64, l15, g);

        f32x4 acc[8];
        #pragma unroll
        for (int cf = 0; cf < 8; ++cf) acc[cf] = (f32x4){0.f, 0.f, 0.f, 0.f};

        #pragma unroll
        for (int c = 0; c < 6; ++c) {
            __bf16* xb = (c & 1) ? xb1 : xb0;
            if ((c & 1) == 0) {
                writeCh(xvE, xb, l15, g);
                if (c + 2 < 6) loadCh(xvE, (c + 2 < 4) ? pi : ps, ((c + 2) & 1) * 64, l15, g);
            } else {
                writeCh(xvO, xb, l15, g);
                if (c + 2 < 6) loadCh(xvO, (c + 2 < 4) ? pi : ps, ((c + 2) & 1) * 64, l15, g);
            }
            computeCh(xb, W1p, c * 2, acc, l15, g);
        }

        // epilogue (R7-verified): score row g*4+r
        #pragma unroll
        for (int r = 0; r < 4; ++r) {
            float psv = 0.f;
            #pragma unroll
            for (int cf = 0; cf < 8; ++cf)
                psv += fmaxf(acc[cf][r] + b1v[cf], 0.f) * w2v[cf];
            psv += __shfl_xor(psv, 1);
            psv += __shfl_xor(psv, 2);
            psv += __shfl_xor(psv, 4);
            psv += __shfl_xor(psv, 8);
            if (l15 == 0)
                scores[t * 16 + g * 4 + r] = psv + b2v;
        }
    }
}

// ---------------- kernel B ----------------
__global__ __launch_bounds__(256, 3) void kB(
    const float* __restrict__ Cc, const float* __restrict__ pss,
    const __bf16* __restrict__ WRp, const float* __restrict__ bR,
    const float* __restrict__ Wot, const float* __restrict__ bo,
    const float* __restrict__ scores, float* __restrict__ out)
{
    __shared__ __align__(16) __bf16 Xw[4][2][1024];
    __shared__ float wsc[4][112];
    __shared__ float prs[4][128];

    const int tid = threadIdx.x;
    const int lane = tid & 63;
    const int wid  = tid >> 6;
    const int g    = lane >> 4;
    const int l15  = lane & 15;
    const int gw = blockIdx.x * 4 + wid;
    const int NW = gridDim.x * 4;

    float bRv[8];
    #pragma unroll
    for (int cf = 0; cf < 8; ++cf) bRv[cf] = bR[cf * 16 + l15];

    __bf16* xb0 = &Xw[wid][0][0];
    __bf16* xb1 = &Xw[wid][1][0];

    for (int m = gw; m < M_; m += NW) {
        // ---- wave-private softmax over this m's 100 scores (R10-verified) ----
        const float* sp = scores + (long)m * N_;
        float s0 = (lane < N_) ? sp[lane] : -3e38f;
        float s1 = (lane + 64 < N_) ? sp[lane + 64] : -3e38f;
        float mx = fmaxf(s0, s1);
        #pragma unroll
        for (int off = 1; off < 64; off <<= 1) mx = fmaxf(mx, __shfl_xor(mx, off));
        float e0 = (lane < N_) ? __expf(s0 - mx) : 0.f;
        float e1 = (lane + 64 < N_) ? __expf(s1 - mx) : 0.f;
        float sum = e0 + e1;
        #pragma unroll
        for (int off = 1; off < 64; off <<= 1) sum += __shfl_xor(sum, off);
        float inv = 1.f / sum;
        wsc[wid][lane] = e0 * inv;
        if (lane < 48) wsc[wid][64 + lane] = e1 * inv;   // rows >=100 get 0

        const float* __restrict__ cb = Cc + (long)m * N_ * E_;
        const float* __restrict__ pb = pss + (long)m * N_ * E_;

        float psum[8];
        #pragma unroll
        for (int cf = 0; cf < 8; ++cf) psum[cf] = 0.f;

        for (int tt = 0; tt < 7; ++tt) {
            const int r0 = tt * 16;
            float4 xvE[4], xvO[4];
            loadChB(xvE, cb, r0, 0, l15, g);
            loadChB(xvO, cb, r0, 64, l15, g);

            f32x4 acc[8];
            #pragma unroll
            for (int cf = 0; cf < 8; ++cf) acc[cf] = (f32x4){0.f, 0.f, 0.f, 0.f};

            #pragma unroll
            for (int c = 0; c < 4; ++c) {
                __bf16* xb = (c & 1) ? xb1 : xb0;
                if ((c & 1) == 0) {
                    writeCh(xvE, xb, l15, g);
                    if (c + 2 < 4) loadChB(xvE, pb, r0, ((c + 2) & 1) * 64, l15, g);
                } else {
                    writeCh(xvO, xb, l15, g);
                    if (c + 2 < 4) loadChB(xvO, pb, r0, ((c + 2) & 1) * 64, l15, g);
                }
                computeCh(xb, WRp, c * 2, acc, l15, g);
            }

            // pooling: tile rows g*4+r (R10-verified)
            float wg[4];
            #pragma unroll
            for (int r = 0; r < 4; ++r) wg[r] = wsc[wid][tt * 16 + g * 4 + r];
            #pragma unroll
            for (int cf = 0; cf < 8; ++cf)
                #pragma unroll
                for (int r = 0; r < 4; ++r)
                    psum[cf] += wg[r] * fmaxf(acc[cf][r] + bRv[cf], 0.f);
        }

        #pragma unroll
        for (int cf = 0; cf < 8; ++cf) {
            psum[cf] += __shfl_xor(psum[cf], 16);
            psum[cf] += __shfl_xor(psum[cf], 32);
            prs[wid][cf * 16 + l15] = psum[cf];   // duplicate writes, same value
        }

        // lout (R10-verified): out[e] = relu(bo[e] + pair . Wot[e])
        float o0 = 0.f, o1 = 0.f;
        #pragma unroll 8
        for (int kb = 0; kb < 32; ++kb) {
            float4 pk  = *reinterpret_cast<const float4*>(&prs[wid][kb * 4]);
            float4 wv0 = *reinterpret_cast<const float4*>(Wot + (long)lane * 128 + kb * 4);
            float4 wv1 = *reinterpret_cast<const float4*>(Wot + (long)(lane + 64) * 128 + kb * 4);
            o0 += pk.x * wv0.x + pk.y * wv0.y + pk.z * wv0.z + pk.w * wv0.w;
            o1 += pk.x * wv1.x + pk.y * wv1.y + pk.z * wv1.z + pk.w * wv1.w;
        }
        out[(long)m * 128 + lane]      = fmaxf(o0 + bo[lane], 0.f);
        out[(long)m * 128 + lane + 64] = fmaxf(o1 + bo[lane + 64], 0.f);
    }
}

extern "C" void kernel_launch(void* const* d_in, const int* in_sizes, int n_in,
                              void* d_out, int out_size, void* d_ws, size_t ws_size,
                              hipStream_t stream) {
    const float* pus = (const float*)d_in[2];
    const float* pis = (const float*)d_in[3];
    const float* pss = (const float*)d_in[4];
    const float* C   = (const float*)d_in[5];
    const float* W1  = (const float*)d_in[6];
    const float* b1  = (const float*)d_in[7];
    const float* W2  = (const float*)d_in[8];
    const float* b2  = (const float*)d_in[9];
    const float* WR  = (const float*)d_in[10];
    const float* bR  = (const float*)d_in[11];
    const float* Wo  = (const float*)d_in[12];
    const float* bo  = (const float*)d_in[13];
    (void)in_sizes; (void)n_in; (void)ws_size;

    // ws: scores f32[R_] | W1p bf16[48*1024] | WRp bf16[32*1024] | Wot f32[16384]
    float*  scores = (float*)d_ws;
    __bf16* W1p = (__bf16*)((char*)d_ws + (size_t)R_ * 4);
    __bf16* WRp = W1p + 48 * 1024;
    float*  Wot = (float*)(WRp + 32 * 1024);

    prep_weights<<<384, 256, 0, stream>>>(W1, WR, Wo, W1p, WRp, Wot);
    kA<<<1024, 256, 0, stream>>>(pus, pis, pss, W1p, b1, W2, b2, scores);
    kB<<<1024, 256, 0, stream>>>(C, pss, WRp, bR, Wot, bo, scores, (float*)d_out);
}

// Round 12
// 257.271 us; speedup vs baseline: 4.5102x; 4.5102x over previous
//
#include <hip/hip_runtime.h>
#include <hip/hip_bf16.h>

// Fused: out[m,:] = relu( (softmax_n(relu([pus|pis|pss]@W1+b1)@W2+b2) .
//                          relu([C|pss]@WR+bR)) @ Wo + bo )
// R12 = R6 geometry (512 thr, 2x4 waves, Xs[2][128][64] XOR-swizzle dbuf,
// 10 K-steps, 1 barrier/step) + W from chunked layout straight to registers
// (no Ws LDS, no global_load_lds, no manual vmcnt) + whole-tile depth-2 X
// prefetch. LDS 35 KB, VGPR ~120 -> 2 blocks x 8 waves = 16 waves/CU, with a
// full 32 KB X tile in flight per block (in-flight-byte limited fix of R4).

#define M_ 4096
#define N_ 100
#define E_ 128

typedef __bf16 bf16x8 __attribute__((ext_vector_type(8)));
typedef float  f32x4  __attribute__((ext_vector_type(4)));

// W1p[ck][n][j] = bf16(W1[ck*8+j][n]), ck<48 (K=384)
// WRp[ck][n][j] = bf16(WR[ck*8+j][n]), ck<32 (K=256)   (R7-verified layout)
__global__ void prep_weights(const float* __restrict__ W1, const float* __restrict__ WR,
                             __bf16* __restrict__ W1p, __bf16* __restrict__ WRp) {
    int i = blockIdx.x * 256 + threadIdx.x;          // 320*256 == 49152+32768
    if (i < 48 * 128 * 8) {
        int ck = i >> 10, n = (i >> 3) & 127, j = i & 7;
        W1p[i] = (__bf16)W1[(ck * 8 + j) * 128 + n];
    } else {
        int t = i - 48 * 128 * 8;
        if (t < 32 * 128 * 8) {
            int ck = t >> 10, n = (t >> 3) & 127, j = t & 7;
            WRp[t] = (__bf16)WR[(ck * 8 + j) * 128 + n];
        }
    }
}

__global__ __launch_bounds__(512, 4) void fused(
    const float* __restrict__ pus, const float* __restrict__ pis,
    const float* __restrict__ pss, const float* __restrict__ Cc,
    const __bf16* __restrict__ W1p, const float* __restrict__ b1,
    const float* __restrict__ W2, const float* __restrict__ b2,
    const __bf16* __restrict__ WRp, const float* __restrict__ bR,
    const float* __restrict__ Wo, const float* __restrict__ bo,
    float* __restrict__ out)
{
    __shared__ __align__(16) __bf16 Xs[2][128][64];   // 32 KB dbuf
    __shared__ float part[4][128];
    __shared__ float sLDS[128];
    __shared__ float wLDS[128];
    __shared__ float pairLDS[128];

    const int tid  = threadIdx.x;
    const int lane = tid & 63;
    const int wid  = tid >> 6;               // 0..7
    const int wr = wid >> 2, wc = wid & 3;   // 2 x 4 wave grid
    const int g    = lane >> 4;              // k-subgroup 0..3
    const int l15  = lane & 15;
    const int m = blockIdx.x;
    const long base = (long)m * (N_ * E_);

    // hoisted small operands
    float w2v[2], b1v[2], bRv[2];
    #pragma unroll
    for (int b = 0; b < 2; ++b) {
        int col = wc * 32 + b * 16 + l15;
        w2v[b] = W2[col]; b1v[b] = b1[col]; bRv[b] = bR[col];
    }
    const float b2v = b2[0];

    float4 xvE[4], xvO[4];

    // X fetch for step `step` (R6-verified): 4 float4/thread; pad rows clamp
    // to row 99 (masked later by softmax mask / weight=0).
    auto fetchX = [&](float4 (&xv)[4], int step) {
        const float* __restrict__ src =
            (step < 2) ? pus : (step < 4) ? pis : (step < 6) ? pss
          : (step < 8) ? Cc : pss;
        const int colbase = (step & 1) << 6;
        #pragma unroll
        for (int i = 0; i < 4; ++i) {
            int c  = tid + 512 * i;
            int r  = c >> 4;
            int rc = (r < N_) ? r : (N_ - 1);
            int k4 = (c & 15) << 2;
            xv[i] = *reinterpret_cast<const float4*>(
                src + base + (long)rc * E_ + colbase + k4);
        }
    };
    // cvt f32->bf16 + XOR-swizzled ds_write (R6-verified)
    auto writeX = [&](float4 (&xv)[4], int buf) {
        #pragma unroll
        for (int i = 0; i < 4; ++i) {
            int c  = tid + 512 * i;
            int r  = c >> 4;
            int k4 = (c & 15) << 2;
            int blk  = k4 >> 3;
            int phys = ((blk ^ (r & 7)) << 3) + (k4 & 7);
            union { __bf16 h[4]; uint2 u; } tw;
            tw.h[0] = (__bf16)xv[i].x; tw.h[1] = (__bf16)xv[i].y;
            tw.h[2] = (__bf16)xv[i].z; tw.h[3] = (__bf16)xv[i].w;
            *reinterpret_cast<uint2*>(&Xs[buf][r][phys]) = tw.u;
        }
    };

    f32x4 acc[4][2] = {};

    // ---- prologue: buf0 = pus(k0-63); X(1) in regs; X(2) in flight ----
    fetchX(xvE, 0);
    fetchX(xvO, 1);
    writeX(xvE, 0);
    fetchX(xvE, 2);
    asm volatile("s_waitcnt lgkmcnt(0)" ::: "memory");
    __builtin_amdgcn_s_barrier();
    __builtin_amdgcn_sched_barrier(0);

    #pragma unroll
    for (int s = 0; s < 10; ++s) {
        const int cur = s & 1;

        // W B-fragments for this step: chunked layout -> 4 x 16B regs (L2-hot)
        const __bf16* __restrict__ Wp = (s < 6) ? W1p : WRp;
        const int ckb = (s < 6) ? s * 8 : (s - 6) * 8;
        bf16x8 wf[2][2];
        #pragma unroll
        for (int ks = 0; ks < 2; ++ks)
            #pragma unroll
            for (int b = 0; b < 2; ++b) {
                int nn = wc * 32 + b * 16 + l15;
                wf[ks][b] = *reinterpret_cast<const bf16x8*>(
                    W1p + 0 + ((long)(ckb + ks * 4 + g) << 10) + nn * 8
                    + (Wp - W1p));
            }
        __builtin_amdgcn_sched_barrier(0);

        // stage next X tile; prefetch X(s+3)
        if (s < 9) {
            if (((s + 1) & 1) == 0) {
                writeX(xvE, cur ^ 1);
                if (s + 3 < 10) fetchX(xvE, s + 3);
            } else {
                writeX(xvO, cur ^ 1);
                if (s + 3 < 10) fetchX(xvO, s + 3);
            }
        }
        __builtin_amdgcn_sched_barrier(0);

        // MFMA cluster on Xs[cur] + wf
        __builtin_amdgcn_s_setprio(1);
        #pragma unroll
        for (int ks = 0; ks < 2; ++ks) {
            const int kblk = (ks << 2) + g;
            bf16x8 af[4];
            #pragma unroll
            for (int a = 0; a < 4; ++a) {
                int rr = wr * 64 + a * 16 + l15;
                af[a] = *reinterpret_cast<const bf16x8*>(
                    &Xs[cur][rr][(kblk ^ (rr & 7)) << 3]);
            }
            #pragma unroll
            for (int a = 0; a < 4; ++a)
                #pragma unroll
                for (int b = 0; b < 2; ++b)
                    acc[a][b] = __builtin_amdgcn_mfma_f32_16x16x32_bf16(
                        af[a], wf[ks][b], acc[a][b], 0, 0, 0);
        }
        __builtin_amdgcn_s_setprio(0);

        if (s == 5) {
            // ---- epilogue A: scores + softmax (R6-verified) ----
            #pragma unroll
            for (int a = 0; a < 4; ++a) {
                #pragma unroll
                for (int r = 0; r < 4; ++r) {
                    float ps = 0.f;
                    #pragma unroll
                    for (int b = 0; b < 2; ++b) {
                        float h = fmaxf(acc[a][b][r] + b1v[b], 0.f);
                        ps += h * w2v[b];
                    }
                    ps += __shfl_xor(ps, 1);
                    ps += __shfl_xor(ps, 2);
                    ps += __shfl_xor(ps, 4);
                    ps += __shfl_xor(ps, 8);
                    if (l15 == 0) {
                        int row = wr * 64 + a * 16 + g * 4 + r;
                        part[wc][row] = ps;
                    }
                }
            }
            asm volatile("s_waitcnt lgkmcnt(0)" ::: "memory");
            __builtin_amdgcn_s_barrier();
            __builtin_amdgcn_sched_barrier(0);
            if (tid < 128)
                sLDS[tid] = part[0][tid] + part[1][tid] + part[2][tid]
                          + part[3][tid] + b2v;
            asm volatile("s_waitcnt lgkmcnt(0)" ::: "memory");
            __builtin_amdgcn_s_barrier();
            __builtin_amdgcn_sched_barrier(0);
            if (wid == 0) {
                float s0 = (lane < N_) ? sLDS[lane] : -3e38f;
                float s1 = (lane + 64 < N_) ? sLDS[lane + 64] : -3e38f;
                float mx = fmaxf(s0, s1);
                #pragma unroll
                for (int off = 1; off < 64; off <<= 1) mx = fmaxf(mx, __shfl_xor(mx, off));
                float e0 = (lane < N_) ? __expf(s0 - mx) : 0.f;
                float e1 = (lane + 64 < N_) ? __expf(s1 - mx) : 0.f;
                float sum = e0 + e1;
                #pragma unroll
                for (int off = 1; off < 64; off <<= 1) sum += __shfl_xor(sum, off);
                float inv = 1.f / sum;
                wLDS[lane]      = e0 * inv;
                wLDS[lane + 64] = e1 * inv;   // pad rows get weight 0
            }
            #pragma unroll
            for (int a = 0; a < 4; ++a)
                #pragma unroll
                for (int b = 0; b < 2; ++b)
                    #pragma unroll
                    for (int q = 0; q < 4; ++q)
                        acc[a][b][q] = 0.f;
        }

        asm volatile("s_waitcnt lgkmcnt(0)" ::: "memory");
        __builtin_amdgcn_s_barrier();
        __builtin_amdgcn_sched_barrier(0);
    }

    // ---- epilogue B: weighted pooling + lout (R6-verified) ----
    {
        float psum[2] = {0.f, 0.f};
        #pragma unroll
        for (int a = 0; a < 4; ++a) {
            #pragma unroll
            for (int r = 0; r < 4; ++r) {
                float wgt = wLDS[wr * 64 + a * 16 + g * 4 + r];
                #pragma unroll
                for (int b = 0; b < 2; ++b) {
                    float v = fmaxf(acc[a][b][r] + bRv[b], 0.f);
                    psum[b] += wgt * v;
                }
            }
        }
        #pragma unroll
        for (int b = 0; b < 2; ++b) {
            psum[b] += __shfl_xor(psum[b], 16);
            psum[b] += __shfl_xor(psum[b], 32);
        }
        if (lane < 16) {
            #pragma unroll
            for (int b = 0; b < 2; ++b)
                part[wr][wc * 32 + b * 16 + lane] = psum[b];
        }
        __syncthreads();
        if (tid < 128) pairLDS[tid] = part[0][tid] + part[1][tid];
        __syncthreads();
        if (tid < 128) {
            float o = bo[tid];
            #pragma unroll 8
            for (int k = 0; k < 128; ++k)
                o += pairLDS[k] * Wo[k * 128 + tid];
            out[(long)m * 128 + tid] = fmaxf(o, 0.f);
        }
    }
}

extern "C" void kernel_launch(void* const* d_in, const int* in_sizes, int n_in,
                              void* d_out, int out_size, void* d_ws, size_t ws_size,
                              hipStream_t stream) {
    const float* pus = (const float*)d_in[2];
    const float* pis = (const float*)d_in[3];
    const float* pss = (const float*)d_in[4];
    const float* C   = (const float*)d_in[5];
    const float* W1  = (const float*)d_in[6];
    const float* b1  = (const float*)d_in[7];
    const float* W2  = (const float*)d_in[8];
    const float* b2  = (const float*)d_in[9];
    const float* WR  = (const float*)d_in[10];
    const float* bR  = (const float*)d_in[11];
    const float* Wo  = (const float*)d_in[12];
    const float* bo  = (const float*)d_in[13];
    (void)in_sizes; (void)n_in; (void)ws_size;

    // workspace: W1p bf16[48*1024] | WRp bf16[32*1024]
    __bf16* W1p = (__bf16*)d_ws;
    __bf16* WRp = W1p + 48 * 1024;

    prep_weights<<<320, 256, 0, stream>>>(W1, WR, W1p, WRp);
    fused<<<M_, 512, 0, stream>>>(pus, pis, pss, C, W1p, b1, W2, b2,
                                  WRp, bR, Wo, bo, (float*)d_out);
}